// Round 5
// baseline (179.526 us; speedup 1.0000x reference)
//
#include <hip/hip_runtime.h>

#define B_N 16
#define C_N 3
#define H_N 512
#define W_N 512
#define PLANES (B_N * C_N)            // 48
#define ROWS_PER_BLOCK 32
#define ROWS_PER_WAVE 8               // in 2 batches of 4
#define CHUNKS (H_N / ROWS_PER_BLOCK) // 16
#define NBLK (PLANES * CHUNKS)        // 768 == 3 blocks/CU exactly
#define STATS3 (W_N * 3)              // 1536
#define SCALE (-1.0f / 8192.0f)       // -1/(B*H) == -1/(B*W), weights all 1
#define EPS_F 1e-12f

// K1: single streaming pass, reads x and ref exactly once.
//  - Pure load+FMA loop: 2 batches x 4 rows/wave; per-row partials for all
//    8 rows live in registers; ALL cross-lane shuffles deferred to the end
//    (24 values x 6 levels, independent).
//  - 768 blocks = exactly 3/CU; 32 rows/block amortizes the LDS epilogue
//    over 128 KB streamed and halves colpart vs R4 (4.7 MB).
//  - LDS + colpart are SoA [3][512]: epilogue writes are float4
//    (ds_write_b128, conflict-free) instead of stride-12 scalar stores.
//  - launch_bounds(256,4): 128-VGPR budget. NOT (256,6) — that spilled
//    ~100 floats/thread to scratch in R3 (WRITE_SIZE 158 MB, 38% BW).
__global__ __launch_bounds__(256, 4) void spl_main_kernel(
    const float* __restrict__ x, const float* __restrict__ r,
    float* __restrict__ colpart, float* __restrict__ rowpart) {
    const int p     = blockIdx.x / CHUNKS;
    const int chunk = blockIdx.x % CHUNKS;
    const int wave  = threadIdx.x >> 6;
    const int lane  = threadIdx.x & 63;

    const float* xp = x + (size_t)p * (H_N * W_N);
    const float* rp = r + (size_t)p * (H_N * W_N);

    float cxx[8] = {0, 0, 0, 0, 0, 0, 0, 0};
    float crr[8] = {0, 0, 0, 0, 0, 0, 0, 0};
    float cxr[8] = {0, 0, 0, 0, 0, 0, 0, 0};
    float psxx[ROWS_PER_WAVE], psrr[ROWS_PER_WAVE], psxr[ROWS_PER_WAVE];

    const int r0 = chunk * ROWS_PER_BLOCK;
    #pragma unroll
    for (int b = 0; b < 2; ++b) {
        #pragma unroll
        for (int j = 0; j < 4; ++j) {
            const int row = r0 + b * 16 + wave * 4 + j;
            const int jj = b * 4 + j;
            const float4* xr4 = (const float4*)(xp + (size_t)row * W_N);
            const float4* rr4 = (const float4*)(rp + (size_t)row * W_N);
            const float4 xa = xr4[lane];
            const float4 xb = xr4[lane + 64];
            const float4 ra = rr4[lane];
            const float4 rb = rr4[lane + 64];

            const float ax[8] = {xa.x, xa.y, xa.z, xa.w, xb.x, xb.y, xb.z, xb.w};
            const float rx[8] = {ra.x, ra.y, ra.z, ra.w, rb.x, rb.y, rb.z, rb.w};

            float sxx = 0.0f, srr = 0.0f, sxr = 0.0f;
            #pragma unroll
            for (int k = 0; k < 8; ++k) {
                const float txx = ax[k] * ax[k];
                const float trr = rx[k] * rx[k];
                const float txr = ax[k] * rx[k];
                cxx[k] += txx; crr[k] += trr; cxr[k] += txr;
                sxx += txx;    srr += trr;    sxr += txr;
            }
            psxx[jj] = sxx; psrr[jj] = srr; psxr[jj] = sxr;
        }
    }

    // deferred cross-lane reductions: 24 values x 6 levels, all independent
    #pragma unroll
    for (int m = 32; m > 0; m >>= 1) {
        #pragma unroll
        for (int j = 0; j < ROWS_PER_WAVE; ++j) {
            psxx[j] += __shfl_down(psxx[j], m, 64);
            psrr[j] += __shfl_down(psrr[j], m, 64);
            psxr[j] += __shfl_down(psxr[j], m, 64);
        }
    }
    float rowacc = 0.0f;
    if (lane == 0) {
        #pragma unroll
        for (int j = 0; j < ROWS_PER_WAVE; ++j) {
            const float nx = fmaxf(sqrtf(psxx[j]), EPS_F);
            const float nr = fmaxf(sqrtf(psrr[j]), EPS_F);
            rowacc += psxr[j] / (nx * nr);
        }
    }

    // combine column partials across the block's 4 waves via LDS (SoA,
    // float4 stores: lane-stride 16 B -> conflict-free ds_write_b128)
    __shared__ float smem[4][3][W_N];  // 24 KiB
    *(float4*)&smem[wave][0][4 * lane]       = make_float4(cxx[0], cxx[1], cxx[2], cxx[3]);
    *(float4*)&smem[wave][0][4 * lane + 256] = make_float4(cxx[4], cxx[5], cxx[6], cxx[7]);
    *(float4*)&smem[wave][1][4 * lane]       = make_float4(crr[0], crr[1], crr[2], crr[3]);
    *(float4*)&smem[wave][1][4 * lane + 256] = make_float4(crr[4], crr[5], crr[6], crr[7]);
    *(float4*)&smem[wave][2][4 * lane]       = make_float4(cxr[0], cxr[1], cxr[2], cxr[3]);
    *(float4*)&smem[wave][2][4 * lane + 256] = make_float4(cxr[4], cxr[5], cxr[6], cxr[7]);
    __shared__ float rowsums[4];
    if (lane == 0) rowsums[wave] = rowacc;
    __syncthreads();

    float* cp = colpart + (size_t)blockIdx.x * STATS3;  // [3][512] per block
    #pragma unroll
    for (int k = 0; k < 6; ++k) {
        const int e = threadIdx.x + 256 * k;
        cp[e] = smem[0][0][e] + smem[1][0][e] + smem[2][0][e] + smem[3][0][e];
    }
    if (threadIdx.x == 0)
        rowpart[blockIdx.x] = rowsums[0] + rowsums[1] + rowsums[2] + rowsums[3];
}

// K2: one block per plane — reduce the 16 chunk partials (SoA [3][512]),
// form the 512 column cosine terms, add the 16 row partial sums.
__global__ __launch_bounds__(256) void spl_reduce_kernel(
    const float* __restrict__ colpart, const float* __restrict__ rowpart,
    float* __restrict__ planesum) {
    const int p = blockIdx.x;
    float acc[6] = {0, 0, 0, 0, 0, 0};
    const float* base = colpart + (size_t)p * CHUNKS * STATS3;
    for (int c = 0; c < CHUNKS; ++c) {
        const float* bc = base + c * STATS3;
        #pragma unroll
        for (int k = 0; k < 6; ++k) acc[k] += bc[threadIdx.x + 256 * k];
    }
    __shared__ float sums[STATS3];  // SoA: [0..511]=sxx, [512..]=srr, [1024..]=sxr
    #pragma unroll
    for (int k = 0; k < 6; ++k) sums[threadIdx.x + 256 * k] = acc[k];
    __syncthreads();

    float term = 0.0f;
    #pragma unroll
    for (int k = 0; k < 2; ++k) {
        const int col = threadIdx.x + 256 * k;
        const float sxx = sums[col];
        const float srr = sums[512 + col];
        const float sxr = sums[1024 + col];
        term += sxr / (fmaxf(sqrtf(sxx), EPS_F) * fmaxf(sqrtf(srr), EPS_F));
    }
    if (threadIdx.x < CHUNKS) term += rowpart[p * CHUNKS + threadIdx.x];

    #pragma unroll
    for (int m = 32; m > 0; m >>= 1) term += __shfl_down(term, m, 64);
    __shared__ float ws[4];
    if ((threadIdx.x & 63) == 0) ws[threadIdx.x >> 6] = term;
    __syncthreads();
    if (threadIdx.x == 0) planesum[p] = ws[0] + ws[1] + ws[2] + ws[3];
}

// K3: one wave folds the 48 plane scalars and writes the output directly.
__global__ void spl_final_kernel(const float* __restrict__ planesum,
                                 float* __restrict__ out) {
    float v = (threadIdx.x < PLANES) ? planesum[threadIdx.x] : 0.0f;
    #pragma unroll
    for (int m = 32; m > 0; m >>= 1) v += __shfl_down(v, m, 64);
    if (threadIdx.x == 0) out[0] = SCALE * v;
}

extern "C" void kernel_launch(void* const* d_in, const int* in_sizes, int n_in,
                              void* d_out, int out_size, void* d_ws, size_t ws_size,
                              hipStream_t stream) {
    const float* x   = (const float*)d_in[0];
    const float* ref = (const float*)d_in[1];
    float* out = (float*)d_out;

    float* colpart  = (float*)d_ws;                       // NBLK*1536 floats (4.7 MB)
    float* rowpart  = colpart + (size_t)NBLK * STATS3;    // NBLK floats
    float* planesum = rowpart + NBLK;                     // 48 floats

    spl_main_kernel<<<NBLK, 256, 0, stream>>>(x, ref, colpart, rowpart);
    spl_reduce_kernel<<<PLANES, 256, 0, stream>>>(colpart, rowpart, planesum);
    spl_final_kernel<<<1, 64, 0, stream>>>(planesum, out);
}

// Round 6
// 120.383 us; speedup vs baseline: 1.4913x; 1.4913x over previous
//
#include <hip/hip_runtime.h>

#define B_N 16
#define C_N 3
#define H_N 512
#define W_N 512
#define PLANES (B_N * C_N)            // 48
#define ROWS_PER_BLOCK 32
#define ROWS_PER_WAVE 8               // in 2 batches of 4
#define CHUNKS (H_N / ROWS_PER_BLOCK) // 16
#define NBLK (PLANES * CHUNKS)        // 768 == 3 blocks/CU exactly
#define STATS3 (W_N * 3)              // 1536
#define SCALE (-1.0f / 8192.0f)       // -1/(B*H) == -1/(B*W), weights all 1
#define EPS_F 1e-12f

// K1: single streaming pass, reads x and ref exactly once.
//  - Pure load+FMA loop: 2 batches x 4 rows/wave; per-row partials for all
//    8 rows live in registers; ALL cross-lane shuffles deferred to the end.
//  - 768 blocks = exactly 3/CU; 32 rows/block amortizes the LDS epilogue.
//  - LDS + colpart are SoA [3][512]: float4 epilogue stores, conflict-free.
//  - __launch_bounds__(256) ONLY — EMPIRICAL (R3/R5): adding a min-waves
//    second arg caps VGPRs at 40 (arg=6) / 64 (arg=4) on this toolchain and
//    spills ~100 floats/thread to scratch (R5: WRITE 127.7 MB vs 4.7 MB
//    payload, 34% BW). With no cap the ~90-reg live set allocates cleanly;
//    grid is 3 blocks/CU co-resident regardless, so occupancy is unchanged.
__global__ __launch_bounds__(256) void spl_main_kernel(
    const float* __restrict__ x, const float* __restrict__ r,
    float* __restrict__ colpart, float* __restrict__ rowpart) {
    const int p     = blockIdx.x / CHUNKS;
    const int chunk = blockIdx.x % CHUNKS;
    const int wave  = threadIdx.x >> 6;
    const int lane  = threadIdx.x & 63;

    const float* xp = x + (size_t)p * (H_N * W_N);
    const float* rp = r + (size_t)p * (H_N * W_N);

    float cxx[8] = {0, 0, 0, 0, 0, 0, 0, 0};
    float crr[8] = {0, 0, 0, 0, 0, 0, 0, 0};
    float cxr[8] = {0, 0, 0, 0, 0, 0, 0, 0};
    float psxx[ROWS_PER_WAVE], psrr[ROWS_PER_WAVE], psxr[ROWS_PER_WAVE];

    const int r0 = chunk * ROWS_PER_BLOCK;
    #pragma unroll
    for (int b = 0; b < 2; ++b) {
        #pragma unroll
        for (int j = 0; j < 4; ++j) {
            const int row = r0 + b * 16 + wave * 4 + j;
            const int jj = b * 4 + j;
            const float4* xr4 = (const float4*)(xp + (size_t)row * W_N);
            const float4* rr4 = (const float4*)(rp + (size_t)row * W_N);
            const float4 xa = xr4[lane];
            const float4 xb = xr4[lane + 64];
            const float4 ra = rr4[lane];
            const float4 rb = rr4[lane + 64];

            const float ax[8] = {xa.x, xa.y, xa.z, xa.w, xb.x, xb.y, xb.z, xb.w};
            const float rx[8] = {ra.x, ra.y, ra.z, ra.w, rb.x, rb.y, rb.z, rb.w};

            float sxx = 0.0f, srr = 0.0f, sxr = 0.0f;
            #pragma unroll
            for (int k = 0; k < 8; ++k) {
                const float txx = ax[k] * ax[k];
                const float trr = rx[k] * rx[k];
                const float txr = ax[k] * rx[k];
                cxx[k] += txx; crr[k] += trr; cxr[k] += txr;
                sxx += txx;    srr += trr;    sxr += txr;
            }
            psxx[jj] = sxx; psrr[jj] = srr; psxr[jj] = sxr;
        }
    }

    // deferred cross-lane reductions: 24 values x 6 levels, all independent
    #pragma unroll
    for (int m = 32; m > 0; m >>= 1) {
        #pragma unroll
        for (int j = 0; j < ROWS_PER_WAVE; ++j) {
            psxx[j] += __shfl_down(psxx[j], m, 64);
            psrr[j] += __shfl_down(psrr[j], m, 64);
            psxr[j] += __shfl_down(psxr[j], m, 64);
        }
    }
    float rowacc = 0.0f;
    if (lane == 0) {
        #pragma unroll
        for (int j = 0; j < ROWS_PER_WAVE; ++j) {
            const float nx = fmaxf(sqrtf(psxx[j]), EPS_F);
            const float nr = fmaxf(sqrtf(psrr[j]), EPS_F);
            rowacc += psxr[j] / (nx * nr);
        }
    }

    // combine column partials across the block's 4 waves via LDS (SoA,
    // float4 stores: lane-stride 16 B -> conflict-free ds_write_b128)
    __shared__ float smem[4][3][W_N];  // 24 KiB
    *(float4*)&smem[wave][0][4 * lane]       = make_float4(cxx[0], cxx[1], cxx[2], cxx[3]);
    *(float4*)&smem[wave][0][4 * lane + 256] = make_float4(cxx[4], cxx[5], cxx[6], cxx[7]);
    *(float4*)&smem[wave][1][4 * lane]       = make_float4(crr[0], crr[1], crr[2], crr[3]);
    *(float4*)&smem[wave][1][4 * lane + 256] = make_float4(crr[4], crr[5], crr[6], crr[7]);
    *(float4*)&smem[wave][2][4 * lane]       = make_float4(cxr[0], cxr[1], cxr[2], cxr[3]);
    *(float4*)&smem[wave][2][4 * lane + 256] = make_float4(cxr[4], cxr[5], cxr[6], cxr[7]);
    __shared__ float rowsums[4];
    if (lane == 0) rowsums[wave] = rowacc;
    __syncthreads();

    float* cp = colpart + (size_t)blockIdx.x * STATS3;  // [3][512] per block
    #pragma unroll
    for (int k = 0; k < 6; ++k) {
        const int e = threadIdx.x + 256 * k;
        cp[e] = smem[0][0][e] + smem[1][0][e] + smem[2][0][e] + smem[3][0][e];
    }
    if (threadIdx.x == 0)
        rowpart[blockIdx.x] = rowsums[0] + rowsums[1] + rowsums[2] + rowsums[3];
}

// K2: one block per plane — reduce the 16 chunk partials (SoA [3][512]),
// form the 512 column cosine terms, add the 16 row partial sums.
__global__ __launch_bounds__(256) void spl_reduce_kernel(
    const float* __restrict__ colpart, const float* __restrict__ rowpart,
    float* __restrict__ planesum) {
    const int p = blockIdx.x;
    float acc[6] = {0, 0, 0, 0, 0, 0};
    const float* base = colpart + (size_t)p * CHUNKS * STATS3;
    for (int c = 0; c < CHUNKS; ++c) {
        const float* bc = base + c * STATS3;
        #pragma unroll
        for (int k = 0; k < 6; ++k) acc[k] += bc[threadIdx.x + 256 * k];
    }
    __shared__ float sums[STATS3];  // SoA: [0..511]=sxx, [512..]=srr, [1024..]=sxr
    #pragma unroll
    for (int k = 0; k < 6; ++k) sums[threadIdx.x + 256 * k] = acc[k];
    __syncthreads();

    float term = 0.0f;
    #pragma unroll
    for (int k = 0; k < 2; ++k) {
        const int col = threadIdx.x + 256 * k;
        const float sxx = sums[col];
        const float srr = sums[512 + col];
        const float sxr = sums[1024 + col];
        term += sxr / (fmaxf(sqrtf(sxx), EPS_F) * fmaxf(sqrtf(srr), EPS_F));
    }
    if (threadIdx.x < CHUNKS) term += rowpart[p * CHUNKS + threadIdx.x];

    #pragma unroll
    for (int m = 32; m > 0; m >>= 1) term += __shfl_down(term, m, 64);
    __shared__ float ws[4];
    if ((threadIdx.x & 63) == 0) ws[threadIdx.x >> 6] = term;
    __syncthreads();
    if (threadIdx.x == 0) planesum[p] = ws[0] + ws[1] + ws[2] + ws[3];
}

// K3: one wave folds the 48 plane scalars and writes the output directly.
__global__ void spl_final_kernel(const float* __restrict__ planesum,
                                 float* __restrict__ out) {
    float v = (threadIdx.x < PLANES) ? planesum[threadIdx.x] : 0.0f;
    #pragma unroll
    for (int m = 32; m > 0; m >>= 1) v += __shfl_down(v, m, 64);
    if (threadIdx.x == 0) out[0] = SCALE * v;
}

extern "C" void kernel_launch(void* const* d_in, const int* in_sizes, int n_in,
                              void* d_out, int out_size, void* d_ws, size_t ws_size,
                              hipStream_t stream) {
    const float* x   = (const float*)d_in[0];
    const float* ref = (const float*)d_in[1];
    float* out = (float*)d_out;

    float* colpart  = (float*)d_ws;                       // NBLK*1536 floats (4.7 MB)
    float* rowpart  = colpart + (size_t)NBLK * STATS3;    // NBLK floats
    float* planesum = rowpart + NBLK;                     // 48 floats

    spl_main_kernel<<<NBLK, 256, 0, stream>>>(x, ref, colpart, rowpart);
    spl_reduce_kernel<<<PLANES, 256, 0, stream>>>(colpart, rowpart, planesum);
    spl_final_kernel<<<1, 64, 0, stream>>>(planesum, out);
}